// Round 1
// baseline (415.679 us; speedup 1.0000x reference)
//
#include <hip/hip_runtime.h>
#include <stdint.h>
#include <stddef.h>

typedef __attribute__((ext_vector_type(4))) float  f32x4;
typedef __attribute__((ext_vector_type(4))) float  float4v;
typedef __attribute__((ext_vector_type(8))) short  short8;
typedef __attribute__((ext_vector_type(4))) short  short4v;

__device__ __forceinline__ unsigned short f2bfbits(float f) {
  unsigned int u = __builtin_bit_cast(unsigned int, f);
  u += 0x7FFFu + ((u >> 16) & 1u);   // RNE
  return (unsigned short)(u >> 16);
}

__device__ __forceinline__ f32x4 mfma16(short8 a, short8 b, f32x4 c) {
  return __builtin_amdgcn_mfma_f32_16x16x32_bf16(a, b, c, 0, 0, 0);
}

__device__ __forceinline__ f32x4 vmax4(f32x4 a, f32x4 b) {
  f32x4 r;
  r[0] = fmaxf(a[0], b[0]); r[1] = fmaxf(a[1], b[1]);
  r[2] = fmaxf(a[2], b[2]); r[3] = fmaxf(a[3], b[3]);
  return r;
}
__device__ __forceinline__ f32x4 shflx4(f32x4 v, int m) {
  f32x4 r;
  r[0] = __shfl_xor(v[0], m); r[1] = __shfl_xor(v[1], m);
  r[2] = __shfl_xor(v[2], m); r[3] = __shfl_xor(v[3], m);
  return r;
}

// ---------------------------------------------------------------- mask prep
// Detect storage layout of the jax bool padding_mask (bool8 / int32 / f32 /
// int64) from byte patterns in the first 4096 bytes (safe in all layouts),
// then expand to an additive f32 bias: 0.0 (keep) or -1e30 (mask).
__global__ void prep_mask(const unsigned char* __restrict__ raw,
                          float* __restrict__ madd, int n) {
  __shared__ int s_na, s_gt, s_m84;
  int t = threadIdx.x;
  if (t == 0) { s_na = 0; s_gt = 0; s_m84 = 0; }
  __syncthreads();
  int na = 0, gt = 0, m84 = 0;
  for (int i = t; i < 4096; i += 256) {
    unsigned char v = raw[i];
    if (v) {
      if (i & 3) na++;
      if ((i & 7) == 4) m84++;
      if (v > 1) gt++;
    }
  }
  atomicAdd(&s_na, na); atomicAdd(&s_gt, gt); atomicAdd(&s_m84, m84);
  __syncthreads();
  int layout;                       // 0=bool8 1=int32 2=float32 3=int64
  if (s_na == 0) layout = s_m84 ? 1 : 3;
  else           layout = s_gt ? 2 : 0;
  for (int i = t; i < n; i += 256) {
    bool mv;
    if (layout == 0)      mv = raw[i] != 0;
    else if (layout == 1) mv = ((const int*)raw)[i] != 0;
    else if (layout == 2) mv = ((const float*)raw)[i] > 0.5f;
    else                  mv = ((const long long*)raw)[i] != 0;
    madd[i] = mv ? 0.0f : -1e30f;
  }
}

// ---------------------------------------------------------------- GEMM-BT
// C[M,N] = A[M,K] * B[N,K]^T + bias[N].  A: f32 or bf16 row-major; B: f32
// row-major; C: f32.  128x128 tile, BK=32, 256 threads (4 waves, 2x2), each
// wave 64x64 via 4x4 fragments of v_mfma_f32_16x16x32_bf16.  Reg-staged LDS
// with on-the-fly f32->bf16; rows padded +8 bf16 to keep ds_read_b128
// bank-aliasing at <=2-way (free).
__device__ __forceinline__ void stage_tile_f32(unsigned short* dst,
                                               const float* src, int ld, int t) {
#pragma unroll
  for (int p = 0; p < 4; ++p) {
    int e = p * 256 + t;            // 1024 chunks of 4 floats = 128x32
    int row = e >> 3;
    int col = (e & 7) << 2;
    float4v v = *(const float4v*)(src + (size_t)row * ld + col);
    short4v o;
    o[0] = (short)f2bfbits(v[0]); o[1] = (short)f2bfbits(v[1]);
    o[2] = (short)f2bfbits(v[2]); o[3] = (short)f2bfbits(v[3]);
    *(short4v*)(dst + row * 40 + col) = o;
  }
}
__device__ __forceinline__ void stage_tile_bf16(unsigned short* dst,
                                                const unsigned short* src,
                                                int ld, int t) {
#pragma unroll
  for (int p = 0; p < 2; ++p) {
    int e = p * 256 + t;            // 512 chunks of 8 bf16 = 128x32
    int row = e >> 2;
    int col = (e & 3) << 3;
    *(short8*)(dst + row * 40 + col) = *(const short8*)(src + (size_t)row * ld + col);
  }
}

template <typename TA>
__global__ __launch_bounds__(256) void gemm_bt(const TA* __restrict__ A,
                                               const float* __restrict__ B,
                                               const float* __restrict__ bias,
                                               float* __restrict__ C,
                                               int M, int N, int K) {
  __shared__ unsigned short As[128 * 40];
  __shared__ unsigned short Bs[128 * 40];
  const int t = threadIdx.x;
  const int l = t & 63, w = t >> 6;
  const int lo = l & 15, hi = l >> 4;
  const int bn = blockIdx.x, bm = blockIdx.y;
  const int wr = w >> 1, wc = w & 1;

  f32x4 acc[4][4] = {};
  const TA* Ab = A + (size_t)bm * 128 * K;
  const float* Bb = B + (size_t)bn * 128 * K;

  for (int kt = 0; kt < K; kt += 32) {
    __syncthreads();
    if constexpr (sizeof(TA) == 4)
      stage_tile_f32(As, (const float*)Ab + kt, K, t);
    else
      stage_tile_bf16(As, (const unsigned short*)Ab + kt, K, t);
    stage_tile_f32(Bs, Bb + kt, K, t);
    __syncthreads();

    short8 af[4], bf[4];
#pragma unroll
    for (int i = 0; i < 4; i++)
      af[i] = *(const short8*)&As[(wr * 64 + i * 16 + lo) * 40 + hi * 8];
#pragma unroll
    for (int i = 0; i < 4; i++)
      bf[i] = *(const short8*)&Bs[(wc * 64 + i * 16 + lo) * 40 + hi * 8];
#pragma unroll
    for (int i = 0; i < 4; i++)
#pragma unroll
      for (int j = 0; j < 4; j++)
        acc[i][j] = mfma16(af[i], bf[j], acc[i][j]);
  }

#pragma unroll
  for (int j = 0; j < 4; j++) {
    int col = bn * 128 + wc * 64 + j * 16 + lo;
    float bv = bias[col];
#pragma unroll
    for (int i = 0; i < 4; i++) {
      int row = bm * 128 + wr * 64 + i * 16 + hi * 4;
#pragma unroll
      for (int r = 0; r < 4; r++)
        C[(size_t)(row + r) * N + col] = acc[i][j][r] + bv;
    }
  }
}

// ---------------------------------------------------------------- LayerNorm
// One wave per (row, head) group of 64 elements; full-wave shfl reduce.
__global__ __launch_bounds__(256) void ln_head(const float* __restrict__ in,
                                               unsigned short* __restrict__ out,
                                               const float* __restrict__ gw,
                                               const float* __restrict__ gb,
                                               int ngroups, int instride,
                                               float outscale) {
  int g = blockIdx.x * 4 + (threadIdx.x >> 6);
  if (g >= ngroups) return;
  int lane = threadIdx.x & 63;
  int row = g >> 4, h = g & 15;
  float v = in[(size_t)row * instride + h * 64 + lane];
  float s = v, sq = v * v;
#pragma unroll
  for (int d = 1; d < 64; d <<= 1) {
    s += __shfl_xor(s, d);
    sq += __shfl_xor(sq, d);
  }
  float mu = s * 0.015625f;
  float var = fmaxf(sq * 0.015625f - mu * mu, 0.0f);
  float rs = rsqrtf(var + 1e-6f);
  float o = ((v - mu) * rs * gw[lane] + gb[lane]) * outscale;
  out[(size_t)row * 1024 + h * 64 + lane] = f2bfbits(o);
}

// ---------------------------------------------------------------- V transpose
// kv f32 [6144][2048] (v = cols 1024..2047) -> vt bf16 [32 bh][64 d][3072 j]
__global__ __launch_bounds__(256) void v_transpose(const float* __restrict__ kv,
                                                   unsigned short* __restrict__ vt) {
  __shared__ float tile[64][65];
  int jt = blockIdx.x, h = blockIdx.y;
  int t = threadIdx.x;
  int r = t >> 2, c0 = (t & 3) << 4;
  const float* src = kv + (size_t)(jt * 64 + r) * 2048 + 1024 + h * 64 + c0;
#pragma unroll
  for (int i = 0; i < 4; i++) {
    float4v v = *(const float4v*)(src + i * 4);
    tile[r][c0 + i * 4 + 0] = v[0];
    tile[r][c0 + i * 4 + 1] = v[1];
    tile[r][c0 + i * 4 + 2] = v[2];
    tile[r][c0 + i * 4 + 3] = v[3];
  }
  __syncthreads();
  int b = (jt * 64) / 3072;
  int j0 = (jt * 64) % 3072;
  int d = t >> 2, jc = (t & 3) << 4;
  unsigned short* dst = vt + (size_t)((b * 16 + h) * 64 + d) * 3072 + j0 + jc;
  short8 o0, o1;
#pragma unroll
  for (int i = 0; i < 8; i++) o0[i] = (short)f2bfbits(tile[jc + i][d]);
#pragma unroll
  for (int i = 0; i < 8; i++) o1[i] = (short)f2bfbits(tile[jc + 8 + i][d]);
  *(short8*)dst = o0;
  *(short8*)(dst + 8) = o1;
}

// ---------------------------------------------------------------- attention
// Flash-style. Grid (16 qblocks, 32 bh), 256 threads. Each wave: 32 q rows.
// KV tile = 64 keys. K/V fragments read directly from global (L2/L3
// resident). P goes through wave-private padded LDS for C->A layout remap.
__global__ __launch_bounds__(256) void attn_fwd(const unsigned short* __restrict__ Q,
                                                const unsigned short* __restrict__ Kn,
                                                const unsigned short* __restrict__ Vt,
                                                const float* __restrict__ maskAdd,
                                                unsigned short* __restrict__ ctx) {
  const int bh = blockIdx.y, b = bh >> 4, h = bh & 15;
  const int t = threadIdx.x, l = t & 63, w = t >> 6;
  const int lo = l & 15, hi = l >> 4;
  const int q0 = blockIdx.x * 128 + w * 32;

  __shared__ unsigned short Plds[4][32][72];   // wave-private, +8 pad

  short8 qf[2][2];
#pragma unroll
  for (int mi = 0; mi < 2; mi++)
#pragma unroll
    for (int g = 0; g < 2; g++)
      qf[mi][g] = *(const short8*)(Q + (size_t)(b * 2048 + q0 + mi * 16 + lo) * 1024 +
                                   h * 64 + g * 32 + hi * 8);

  f32x4 O[2][4] = {};
  float mr[2][4], lr[2][4];
#pragma unroll
  for (int mi = 0; mi < 2; mi++)
#pragma unroll
    for (int r = 0; r < 4; r++) { mr[mi][r] = -1e30f; lr[mi][r] = 0.0f; }

  const unsigned short* Kb = Kn + (size_t)b * 3072 * 1024 + h * 64;
  const unsigned short* Vb = Vt + (size_t)bh * 64 * 3072;
  const float* mb = maskAdd + b * 3072;

  for (int kt = 0; kt < 3072; kt += 64) {
    f32x4 s[2][4] = {};
#pragma unroll
    for (int nf = 0; nf < 4; nf++) {
#pragma unroll
      for (int g = 0; g < 2; g++) {
        short8 kf = *(const short8*)(Kb + (size_t)(kt + nf * 16 + lo) * 1024 +
                                     g * 32 + hi * 8);
        s[0][nf] = mfma16(qf[0][g], kf, s[0][nf]);
        s[1][nf] = mfma16(qf[1][g], kf, s[1][nf]);
      }
      float ma = mb[kt + nf * 16 + lo];
#pragma unroll
      for (int mi = 0; mi < 2; mi++)
#pragma unroll
        for (int r = 0; r < 4; r++) s[mi][nf][r] += ma;
    }

#pragma unroll
    for (int mi = 0; mi < 2; mi++) {
      f32x4 pm = vmax4(vmax4(s[mi][0], s[mi][1]), vmax4(s[mi][2], s[mi][3]));
#pragma unroll
      for (int d = 1; d < 16; d <<= 1) pm = vmax4(pm, shflx4(pm, d));
      float alpha[4];
#pragma unroll
      for (int r = 0; r < 4; r++) {
        float mn = fmaxf(mr[mi][r], pm[r]);
        alpha[r] = __expf(mr[mi][r] - mn);
        mr[mi][r] = mn;
      }
      f32x4 rs = {};
#pragma unroll
      for (int nf = 0; nf < 4; nf++)
#pragma unroll
        for (int r = 0; r < 4; r++) {
          float p = __expf(s[mi][nf][r] - mr[mi][r]);
          s[mi][nf][r] = p;
          rs[r] += p;
        }
#pragma unroll
      for (int d = 1; d < 16; d <<= 1) rs = rs + shflx4(rs, d);
#pragma unroll
      for (int r = 0; r < 4; r++) lr[mi][r] = lr[mi][r] * alpha[r] + rs[r];
#pragma unroll
      for (int df = 0; df < 4; df++)
#pragma unroll
        for (int r = 0; r < 4; r++) O[mi][df][r] *= alpha[r];
#pragma unroll
      for (int nf = 0; nf < 4; nf++)
#pragma unroll
        for (int r = 0; r < 4; r++)
          Plds[w][mi * 16 + hi * 4 + r][nf * 16 + lo] = f2bfbits(s[mi][nf][r]);
    }

    short8 pa0[2], pa1[2];
#pragma unroll
    for (int ks = 0; ks < 2; ks++) {
      pa0[ks] = *(const short8*)&Plds[w][lo][ks * 32 + hi * 8];
      pa1[ks] = *(const short8*)&Plds[w][16 + lo][ks * 32 + hi * 8];
    }
#pragma unroll
    for (int df = 0; df < 4; df++) {
#pragma unroll
      for (int ks = 0; ks < 2; ks++) {
        short8 vf = *(const short8*)(Vb + (size_t)(df * 16 + lo) * 3072 + kt +
                                     ks * 32 + hi * 8);
        O[0][df] = mfma16(pa0[ks], vf, O[0][df]);
        O[1][df] = mfma16(pa1[ks], vf, O[1][df]);
      }
    }
  }

#pragma unroll
  for (int mi = 0; mi < 2; mi++) {
    float inv[4];
#pragma unroll
    for (int r = 0; r < 4; r++) inv[r] = 1.0f / lr[mi][r];
#pragma unroll
    for (int df = 0; df < 4; df++)
#pragma unroll
      for (int r = 0; r < 4; r++)
        ctx[(size_t)(b * 2048 + q0 + mi * 16 + hi * 4 + r) * 1024 + h * 64 +
            df * 16 + lo] = f2bfbits(O[mi][df][r] * inv[r]);
  }
}

// ---------------------------------------------------------------- launch
extern "C" void kernel_launch(void* const* d_in, const int* in_sizes, int n_in,
                              void* d_out, int out_size, void* d_ws, size_t ws_size,
                              hipStream_t stream) {
  const float* x   = (const float*)d_in[0];
  const float* y   = (const float*)d_in[1];
  const unsigned char* pmask = (const unsigned char*)d_in[2];
  const float* Wq  = (const float*)d_in[3];
  const float* bq  = (const float*)d_in[4];
  const float* Wkv = (const float*)d_in[5];
  const float* bkv = (const float*)d_in[6];
  const float* qnw = (const float*)d_in[7];
  const float* qnb = (const float*)d_in[8];
  const float* knw = (const float*)d_in[9];
  const float* knb = (const float*)d_in[10];
  const float* Wo  = (const float*)d_in[11];
  const float* bo  = (const float*)d_in[12];
  float* out = (float*)d_out;

  const size_t MB = 1024ull * 1024ull;
  char* ws = (char*)d_ws;
  float* maskAdd        = (float*)ws;                              // 24 KB
  float* qbuf           = (float*)(ws + 32768);                    // 16 MiB
  float* kvbuf          = (float*)(ws + 32768 + 16 * MB);          // 48 MiB
  unsigned short* qln   = (unsigned short*)(ws + 32768 + 64 * MB); //  8 MiB
  unsigned short* kln   = (unsigned short*)(ws + 32768 + 72 * MB); // 12 MiB
  unsigned short* vt    = (unsigned short*)(ws + 32768 + 84 * MB); // 12 MiB
  unsigned short* ctxb  = (unsigned short*)(ws + 32768 + 96 * MB); //  8 MiB
  if (ws_size < 32768 + 104 * MB) return;  // fail loudly (wrong answer), no OOB

  prep_mask<<<dim3(1), dim3(256), 0, stream>>>(pmask, maskAdd, 6144);

  // q = x @ Wq^T + bq   : M=4096 N=1024 K=1024
  gemm_bt<float><<<dim3(8, 32), dim3(256), 0, stream>>>(x, Wq, bq, qbuf, 4096, 1024, 1024);
  // kv = y @ Wkv^T + bkv: M=6144 N=2048 K=1024
  gemm_bt<float><<<dim3(16, 48), dim3(256), 0, stream>>>(y, Wkv, bkv, kvbuf, 6144, 2048, 1024);

  // LN(q)*scale -> bf16 ; LN(k) -> bf16 ; V -> bf16 transposed
  ln_head<<<dim3(4096 * 16 / 4), dim3(256), 0, stream>>>(qbuf, qln, qnw, qnb, 4096 * 16, 1024, 0.125f);
  ln_head<<<dim3(6144 * 16 / 4), dim3(256), 0, stream>>>(kvbuf, kln, knw, knb, 6144 * 16, 2048, 1.0f);
  v_transpose<<<dim3(96, 16), dim3(256), 0, stream>>>(kvbuf, vt);

  attn_fwd<<<dim3(16, 32), dim3(256), 0, stream>>>(qln, kln, vt, maskAdd, ctxb);

  // out = ctx @ Wo^T + bo : M=4096 N=1024 K=1024
  gemm_bt<unsigned short><<<dim3(8, 32), dim3(256), 0, stream>>>(ctxb, Wo, bo, out, 4096, 1024, 1024);
}

// Round 2
// 387.705 us; speedup vs baseline: 1.0722x; 1.0722x over previous
//
#include <hip/hip_runtime.h>
#include <stdint.h>
#include <stddef.h>

typedef __attribute__((ext_vector_type(4))) float  f32x4;
typedef __attribute__((ext_vector_type(8))) short  short8;
typedef __attribute__((ext_vector_type(4))) short  short4v;
typedef __attribute__((ext_vector_type(2))) unsigned int uint2v;

__device__ __forceinline__ unsigned short f2bfbits(float f) {
  unsigned int u = __builtin_bit_cast(unsigned int, f);
  u += 0x7FFFu + ((u >> 16) & 1u);   // RNE
  return (unsigned short)(u >> 16);
}

__device__ __forceinline__ f32x4 mfma16(short8 a, short8 b, f32x4 c) {
  return __builtin_amdgcn_mfma_f32_16x16x32_bf16(a, b, c, 0, 0, 0);
}

__device__ __forceinline__ unsigned int cvtpk(float a, float b) {
  unsigned int r;
  asm volatile("v_cvt_pk_bf16_f32 %0, %1, %2" : "=v"(r) : "v"(a), "v"(b));
  return r;
}

__device__ __forceinline__ f32x4 vmax4(f32x4 a, f32x4 b) {
  f32x4 r;
  r[0] = fmaxf(a[0], b[0]); r[1] = fmaxf(a[1], b[1]);
  r[2] = fmaxf(a[2], b[2]); r[3] = fmaxf(a[3], b[3]);
  return r;
}

__device__ __forceinline__ void gload16(const void* g, void* l) {
  __builtin_amdgcn_global_load_lds(
      (const __attribute__((address_space(1))) void*)g,
      (__attribute__((address_space(3))) void*)l, 16, 0, 0);
}

// ---------------------------------------------------------------- mask prep
__global__ void prep_mask(const unsigned char* __restrict__ raw,
                          float* __restrict__ madd, int n) {
  __shared__ int s_na, s_gt, s_m84;
  int t = threadIdx.x;
  if (t == 0) { s_na = 0; s_gt = 0; s_m84 = 0; }
  __syncthreads();
  int na = 0, gt = 0, m84 = 0;
  for (int i = t; i < 4096; i += 256) {
    unsigned char v = raw[i];
    if (v) {
      if (i & 3) na++;
      if ((i & 7) == 4) m84++;
      if (v > 1) gt++;
    }
  }
  atomicAdd(&s_na, na); atomicAdd(&s_gt, gt); atomicAdd(&s_m84, m84);
  __syncthreads();
  int layout;                       // 0=bool8 1=int32 2=float32 3=int64
  if (s_na == 0) layout = s_m84 ? 1 : 3;
  else           layout = s_gt ? 2 : 0;
  for (int i = t; i < n; i += 256) {
    bool mv;
    if (layout == 0)      mv = raw[i] != 0;
    else if (layout == 1) mv = ((const int*)raw)[i] != 0;
    else if (layout == 2) mv = ((const float*)raw)[i] > 0.5f;
    else                  mv = ((const long long*)raw)[i] != 0;
    madd[i] = mv ? 0.0f : -1e30f;
  }
}

// ---------------------------------------------------------------- f32->bf16
__global__ __launch_bounds__(256) void cvt_bf16(const float* __restrict__ in,
                                                unsigned short* __restrict__ out,
                                                int n8) {
  int i = blockIdx.x * 256 + threadIdx.x;
  int stride = gridDim.x * 256;
  for (; i < n8; i += stride) {
    f32x4 a = *(const f32x4*)(in + (size_t)i * 8);
    f32x4 b = *(const f32x4*)(in + (size_t)i * 8 + 4);
    short8 o;
    o[0] = (short)f2bfbits(a[0]); o[1] = (short)f2bfbits(a[1]);
    o[2] = (short)f2bfbits(a[2]); o[3] = (short)f2bfbits(a[3]);
    o[4] = (short)f2bfbits(b[0]); o[5] = (short)f2bfbits(b[1]);
    o[6] = (short)f2bfbits(b[2]); o[7] = (short)f2bfbits(b[3]);
    *(short8*)(out + (size_t)i * 8) = o;
  }
}

// ---------------------------------------------------------------- GEMM-BT
// C[M,N] = A[M,K]*B[N,K]^T + bias.  A,B bf16 row-major; C f32.
// 128x128 tile, BK=64, 256 thr (4 waves 2x2), global_load_lds width 16 with
// XOR-swizzled global source + swizzled ds_read_b128 (rule #21 involution).
// kvmode=1: bn<8 -> f32 kbuf; bn>=8 -> bf16 V^T scatter (fused v_transpose).
__global__ __launch_bounds__(256) void gemm_bt16(
    const unsigned short* __restrict__ A, const unsigned short* __restrict__ B,
    const float* __restrict__ bias, float* __restrict__ C,
    unsigned short* __restrict__ vtout, int M, int N, int K, int ldc, int kvmode) {
  __shared__ unsigned short As[128 * 64];
  __shared__ unsigned short Bs[128 * 64];
  const int t = threadIdx.x, l = t & 63, w = t >> 6;
  const int lo = l & 15, hi = l >> 4;
  const int wr = w >> 1, wc = w & 1;
  const int bn = blockIdx.x, bm = blockIdx.y;

  // staging: chunk c = w*4+p covers tile rows c*8..c*8+7 (1KB per instr)
  const int sr = l >> 3;                       // row within chunk
  const int sc = ((l & 7) ^ sr) << 3;          // swizzled col (elements)
  const unsigned short* Ab = A + (size_t)bm * 128 * K + (size_t)sr * K + sc;
  const unsigned short* Bb = B + (size_t)bn * 128 * K + (size_t)sr * K + sc;

  f32x4 acc[4][4] = {};

  for (int kt = 0; kt < K; kt += 64) {
    __syncthreads();
#pragma unroll
    for (int p = 0; p < 4; ++p) {
      int c = w * 4 + p;
      gload16(Ab + (size_t)c * 8 * K + kt, &As[c * 512]);
      gload16(Bb + (size_t)c * 8 * K + kt, &Bs[c * 512]);
    }
    __syncthreads();   // drains vmcnt(0): LDS data ready
#pragma unroll
    for (int kk = 0; kk < 2; ++kk) {
      short8 af[4], bf[4];
#pragma unroll
      for (int i = 0; i < 4; ++i) {
        int slot = (((kk * 4 + hi) ^ (lo & 7)) << 3);
        af[i] = *(const short8*)&As[(wr * 64 + i * 16 + lo) * 64 + slot];
        bf[i] = *(const short8*)&Bs[(wc * 64 + i * 16 + lo) * 64 + slot];
      }
#pragma unroll
      for (int i = 0; i < 4; ++i)
#pragma unroll
        for (int j = 0; j < 4; ++j)
          acc[i][j] = mfma16(af[i], bf[j], acc[i][j]);
    }
  }

  if (kvmode == 0 || bn < 8) {
#pragma unroll
    for (int j = 0; j < 4; ++j) {
      int col = bn * 128 + wc * 64 + j * 16 + lo;
      float bv = bias[col];
#pragma unroll
      for (int i = 0; i < 4; ++i) {
        int row = bm * 128 + wr * 64 + i * 16 + hi * 4;
#pragma unroll
        for (int r = 0; r < 4; ++r)
          C[(size_t)(row + r) * ldc + col] = acc[i][j][r] + bv;
      }
    }
  } else {
    // V portion: cols 1024..2047 = (h,d); scatter bf16 to vt[bh][d][3072]
#pragma unroll
    for (int j = 0; j < 4; ++j) {
      int col = bn * 128 + wc * 64 + j * 16 + lo;
      float bv = bias[col];
      int vcol = col - 1024, hh = vcol >> 6, dd = vcol & 63;
#pragma unroll
      for (int i = 0; i < 4; ++i) {
        int row = bm * 128 + wr * 64 + i * 16 + hi * 4;
        int bb = row >= 3072;
        int jj = row - bb * 3072;
        short4v o;
#pragma unroll
        for (int r = 0; r < 4; ++r) o[r] = (short)f2bfbits(acc[i][j][r] + bv);
        *(short4v*)(vtout + ((size_t)((bb * 16 + hh) * 64 + dd)) * 3072 + jj) = o;
      }
    }
  }
}

// ---------------------------------------------------------------- LayerNorm
// One wave per (row, head) 64-elem group; output head-major [b][h][row][64].
__global__ __launch_bounds__(256) void ln_head(const float* __restrict__ in,
                                               unsigned short* __restrict__ out,
                                               const float* __restrict__ gw,
                                               const float* __restrict__ gb,
                                               int ngroups, int instride, int rpb,
                                               float outscale) {
  int g = blockIdx.x * 4 + (threadIdx.x >> 6);
  if (g >= ngroups) return;
  int lane = threadIdx.x & 63;
  int row = g >> 4, h = g & 15;
  float v = in[(size_t)row * instride + h * 64 + lane];
  float s = v, sq = v * v;
#pragma unroll
  for (int d = 1; d < 64; d <<= 1) {
    s += __shfl_xor(s, d);
    sq += __shfl_xor(sq, d);
  }
  float mu = s * 0.015625f;
  float var = fmaxf(sq * 0.015625f - mu * mu, 0.0f);
  float rs = rsqrtf(var + 1e-6f);
  float o = ((v - mu) * rs * gw[lane] + gb[lane]) * outscale;
  int b = row / rpb, rr = row - b * rpb;
  out[((size_t)(b * 16 + h) * rpb + rr) * 64 + lane] = f2bfbits(o);
}

// ---------------------------------------------------------------- attention
// Swapped QK^T flash attention. Grid (16 qb, 32 bh) XCD-swizzled; 4 waves,
// 32 q/wave. S^T = mfma(K,Q): lane(lo,hi) holds S[q=lo][k=hi*4+r] -> in-lane
// row stats + 2 shuffles. exp2 domain (log2e folded into q scale). P packed
// via v_cvt_pk_bf16_f32, remapped through wave-private LDS (b64 w / b128 r).
__global__ __launch_bounds__(256) void attn_fwd(
    const unsigned short* __restrict__ Q, const unsigned short* __restrict__ Kn,
    const unsigned short* __restrict__ Vt, const float* __restrict__ maskAdd,
    unsigned short* __restrict__ ctx) {
  int flat = blockIdx.y * 16 + blockIdx.x;
  int f = (flat & 7) * 64 + (flat >> 3);        // XCD i owns bh in [4i,4i+4)
  const int bh = f >> 4, qb = f & 15;
  const int b = bh >> 4, h = bh & 15;
  const int t = threadIdx.x, l = t & 63, w = t >> 6;
  const int lo = l & 15, hi = l >> 4;
  const int q0 = qb * 128 + w * 32;

  __shared__ unsigned short Plds[4][32][72];    // 144B row stride: banks ok
  unsigned short (*P)[72] = Plds[w];

  const unsigned short* Qh = Q + ((size_t)bh * 2048 + q0) * 64;
  const unsigned short* Kb = Kn + (size_t)bh * 3072 * 64;
  const unsigned short* Vb = Vt + (size_t)bh * 64 * 3072;
  const float* mb = maskAdd + b * 3072;

  short8 qf[2][2];
#pragma unroll
  for (int mi = 0; mi < 2; mi++)
#pragma unroll
    for (int g = 0; g < 2; g++)
      qf[mi][g] = *(const short8*)(Qh + (size_t)(mi * 16 + lo) * 64 + g * 32 + hi * 8);

  f32x4 O[2][4] = {};
  float mr[2] = {-1e30f, -1e30f}, lr[2] = {0.0f, 0.0f};

  for (int kt = 0; kt < 3072; kt += 64) {
    f32x4 s[2][4] = {};
#pragma unroll
    for (int nf = 0; nf < 4; nf++) {
      const unsigned short* kp = Kb + (size_t)(kt + nf * 16 + lo) * 64 + hi * 8;
      short8 k0 = *(const short8*)kp;
      short8 k1 = *(const short8*)(kp + 32);
      s[0][nf] = mfma16(k0, qf[0][0], s[0][nf]);
      s[0][nf] = mfma16(k1, qf[0][1], s[0][nf]);
      s[1][nf] = mfma16(k0, qf[1][0], s[1][nf]);
      s[1][nf] = mfma16(k1, qf[1][1], s[1][nf]);
    }
#pragma unroll
    for (int nf = 0; nf < 4; nf++) {
      f32x4 mv = *(const f32x4*)(mb + kt + nf * 16 + hi * 4);
      s[0][nf] += mv;
      s[1][nf] += mv;
    }

#pragma unroll
    for (int mi = 0; mi < 2; mi++) {
      f32x4 x4 = vmax4(vmax4(s[mi][0], s[mi][1]), vmax4(s[mi][2], s[mi][3]));
      float pm = fmaxf(fmaxf(x4[0], x4[1]), fmaxf(x4[2], x4[3]));
      pm = fmaxf(pm, __shfl_xor(pm, 16));
      pm = fmaxf(pm, __shfl_xor(pm, 32));
      if (!__all(pm <= mr[mi] + 8.0f)) {        // defer-max (T13)
        float mn = fmaxf(mr[mi], pm);
        float al = __builtin_amdgcn_exp2f(mr[mi] - mn);
        mr[mi] = mn;
        lr[mi] *= al;
        float a0 = __shfl(al, hi * 4 + 0), a1 = __shfl(al, hi * 4 + 1);
        float a2 = __shfl(al, hi * 4 + 2), a3 = __shfl(al, hi * 4 + 3);
#pragma unroll
        for (int df = 0; df < 4; df++) {
          O[mi][df][0] *= a0; O[mi][df][1] *= a1;
          O[mi][df][2] *= a2; O[mi][df][3] *= a3;
        }
      }
      f32x4 ls = {};
#pragma unroll
      for (int nf = 0; nf < 4; nf++) {
#pragma unroll
        for (int r = 0; r < 4; r++)
          s[mi][nf][r] = __builtin_amdgcn_exp2f(s[mi][nf][r] - mr[mi]);
        ls += s[mi][nf];
      }
      float rs = (ls[0] + ls[1]) + (ls[2] + ls[3]);
      rs += __shfl_xor(rs, 16);
      rs += __shfl_xor(rs, 32);
      lr[mi] += rs;
#pragma unroll
      for (int nf = 0; nf < 4; nf++) {
        uint2v u;
        u.x = cvtpk(s[mi][nf][0], s[mi][nf][1]);
        u.y = cvtpk(s[mi][nf][2], s[mi][nf][3]);
        *(uint2v*)&P[mi * 16 + lo][nf * 16 + hi * 4] = u;
      }
    }

    short8 pa[2][2];
#pragma unroll
    for (int mi = 0; mi < 2; mi++)
#pragma unroll
      for (int ks = 0; ks < 2; ks++)
        pa[mi][ks] = *(const short8*)&P[mi * 16 + lo][ks * 32 + hi * 8];
#pragma unroll
    for (int df = 0; df < 4; df++) {
      const unsigned short* vp = Vb + (size_t)(df * 16 + lo) * 3072 + kt + hi * 8;
#pragma unroll
      for (int ks = 0; ks < 2; ks++) {
        short8 vf = *(const short8*)(vp + ks * 32);
        O[0][df] = mfma16(pa[0][ks], vf, O[0][df]);
        O[1][df] = mfma16(pa[1][ks], vf, O[1][df]);
      }
    }
  }

#pragma unroll
  for (int mi = 0; mi < 2; mi++) {
    float i0 = 1.0f / __shfl(lr[mi], hi * 4 + 0);
    float i1 = 1.0f / __shfl(lr[mi], hi * 4 + 1);
    float i2 = 1.0f / __shfl(lr[mi], hi * 4 + 2);
    float i3 = 1.0f / __shfl(lr[mi], hi * 4 + 3);
    size_t rbase = (size_t)b * 2048 + q0 + mi * 16 + hi * 4;
#pragma unroll
    for (int df = 0; df < 4; df++) {
      int cc = h * 64 + df * 16 + lo;
      ctx[(rbase + 0) * 1024 + cc] = f2bfbits(O[mi][df][0] * i0);
      ctx[(rbase + 1) * 1024 + cc] = f2bfbits(O[mi][df][1] * i1);
      ctx[(rbase + 2) * 1024 + cc] = f2bfbits(O[mi][df][2] * i2);
      ctx[(rbase + 3) * 1024 + cc] = f2bfbits(O[mi][df][3] * i3);
    }
  }
}

// ---------------------------------------------------------------- launch
extern "C" void kernel_launch(void* const* d_in, const int* in_sizes, int n_in,
                              void* d_out, int out_size, void* d_ws, size_t ws_size,
                              hipStream_t stream) {
  const float* x   = (const float*)d_in[0];
  const float* y   = (const float*)d_in[1];
  const unsigned char* pmask = (const unsigned char*)d_in[2];
  const float* Wq  = (const float*)d_in[3];
  const float* bq  = (const float*)d_in[4];
  const float* Wkv = (const float*)d_in[5];
  const float* bkv = (const float*)d_in[6];
  const float* qnw = (const float*)d_in[7];
  const float* qnb = (const float*)d_in[8];
  const float* knw = (const float*)d_in[9];
  const float* knb = (const float*)d_in[10];
  const float* Wo  = (const float*)d_in[11];
  const float* bo  = (const float*)d_in[12];
  float* out = (float*)d_out;

  const size_t MB = 1024ull * 1024ull;
  char* ws = (char*)d_ws;
  float* maskAdd       = (float*)ws;                               // 24 KB
  unsigned short* Wqb  = (unsigned short*)(ws + 32768);            //  2 MiB
  unsigned short* Wkvb = (unsigned short*)(ws + 32768 + 2 * MB);   //  4 MiB
  unsigned short* Wob  = (unsigned short*)(ws + 32768 + 6 * MB);   //  2 MiB
  unsigned short* qln  = (unsigned short*)(ws + 32768 + 8 * MB);   //  8 MiB
  unsigned short* kln  = (unsigned short*)(ws + 32768 + 16 * MB);  // 12 MiB
  unsigned short* vt   = (unsigned short*)(ws + 32768 + 28 * MB);  // 12 MiB
  unsigned short* ctxb = (unsigned short*)(ws + 32768 + 40 * MB);  //  8 MiB
  float* qbuf          = (float*)(ws + 32768 + 48 * MB);           // 16 MiB
  float* kbuf          = (float*)(ws + 32768 + 64 * MB);           // 24 MiB
  // aliases (non-overlapping lifetimes):
  unsigned short* xb   = ctxb;  // dead after q-GEMM; ctxb written by attn
  unsigned short* yb   = kln;   // dead after kv-GEMM; kln written by ln_k
  if (ws_size < 32768 + 88 * MB) return;

  prep_mask<<<dim3(1), dim3(256), 0, stream>>>(pmask, maskAdd, 6144);

  // f32 -> bf16 converts (x, y, Wq, Wkv, Wo)
  cvt_bf16<<<dim3(2048), dim3(256), 0, stream>>>(x,   xb,   4194304 / 8);
  cvt_bf16<<<dim3(2048), dim3(256), 0, stream>>>(y,   yb,   6291456 / 8);
  cvt_bf16<<<dim3(512),  dim3(256), 0, stream>>>(Wq,  Wqb,  1048576 / 8);
  cvt_bf16<<<dim3(1024), dim3(256), 0, stream>>>(Wkv, Wkvb, 2097152 / 8);
  cvt_bf16<<<dim3(512),  dim3(256), 0, stream>>>(Wo,  Wob,  1048576 / 8);

  // q = x@Wq^T + bq
  gemm_bt16<<<dim3(8, 32), dim3(256), 0, stream>>>(xb, Wqb, bq, qbuf, nullptr,
                                                   4096, 1024, 1024, 1024, 0);
  // kv = y@Wkv^T + bkv; K-half -> kbuf f32, V-half -> vt bf16 (fused transpose)
  gemm_bt16<<<dim3(16, 48), dim3(256), 0, stream>>>(yb, Wkvb, bkv, kbuf, vt,
                                                    6144, 2048, 1024, 1024, 1);

  // per-head LN; q scaled by d^-1/2 * log2(e) (exp2-domain softmax)
  ln_head<<<dim3(4096 * 16 / 4), dim3(256), 0, stream>>>(
      qbuf, qln, qnw, qnb, 4096 * 16, 1024, 2048, 0.125f * 1.44269504f);
  ln_head<<<dim3(6144 * 16 / 4), dim3(256), 0, stream>>>(
      kbuf, kln, knw, knb, 6144 * 16, 1024, 3072, 1.0f);

  attn_fwd<<<dim3(16, 32), dim3(256), 0, stream>>>(qln, kln, vt, maskAdd, ctxb);

  // out = ctx@Wo^T + bo
  gemm_bt16<<<dim3(8, 32), dim3(256), 0, stream>>>(ctxb, Wob, bo, out, nullptr,
                                                   4096, 1024, 1024, 1024, 0);
}

// Round 3
// 251.894 us; speedup vs baseline: 1.6502x; 1.5392x over previous
//
#include <hip/hip_runtime.h>
#include <stdint.h>
#include <stddef.h>

typedef __attribute__((ext_vector_type(4))) float  f32x4;
typedef __attribute__((ext_vector_type(8))) short  short8;
typedef __attribute__((ext_vector_type(4))) short  short4v;
typedef __attribute__((ext_vector_type(2))) unsigned int uint2v;

__device__ __forceinline__ unsigned short f2bfbits(float f) {
  unsigned int u = __builtin_bit_cast(unsigned int, f);
  u += 0x7FFFu + ((u >> 16) & 1u);   // RNE
  return (unsigned short)(u >> 16);
}

__device__ __forceinline__ f32x4 mfma16(short8 a, short8 b, f32x4 c) {
  return __builtin_amdgcn_mfma_f32_16x16x32_bf16(a, b, c, 0, 0, 0);
}

__device__ __forceinline__ unsigned int cvtpk(float a, float b) {
  unsigned int r;
  asm volatile("v_cvt_pk_bf16_f32 %0, %1, %2" : "=v"(r) : "v"(a), "v"(b));
  return r;
}

__device__ __forceinline__ f32x4 vmax4(f32x4 a, f32x4 b) {
  f32x4 r;
  r[0] = fmaxf(a[0], b[0]); r[1] = fmaxf(a[1], b[1]);
  r[2] = fmaxf(a[2], b[2]); r[3] = fmaxf(a[3], b[3]);
  return r;
}

__device__ __forceinline__ void gload16(const void* g, void* l) {
  __builtin_amdgcn_global_load_lds(
      (const __attribute__((address_space(1))) void*)g,
      (__attribute__((address_space(3))) void*)l, 16, 0, 0);
}

// ---------------------------------------------------------------- mask prep
__global__ void prep_mask(const unsigned char* __restrict__ raw,
                          float* __restrict__ madd, int n) {
  __shared__ int s_na, s_gt, s_m84;
  int t = threadIdx.x;
  if (t == 0) { s_na = 0; s_gt = 0; s_m84 = 0; }
  __syncthreads();
  int na = 0, gt = 0, m84 = 0;
  for (int i = t; i < 4096; i += 256) {
    unsigned char v = raw[i];
    if (v) {
      if (i & 3) na++;
      if ((i & 7) == 4) m84++;
      if (v > 1) gt++;
    }
  }
  atomicAdd(&s_na, na); atomicAdd(&s_gt, gt); atomicAdd(&s_m84, m84);
  __syncthreads();
  int layout;                       // 0=bool8 1=int32 2=float32 3=int64
  if (s_na == 0) layout = s_m84 ? 1 : 3;
  else           layout = s_gt ? 2 : 0;
  for (int i = t; i < n; i += 256) {
    bool mv;
    if (layout == 0)      mv = raw[i] != 0;
    else if (layout == 1) mv = ((const int*)raw)[i] != 0;
    else if (layout == 2) mv = ((const float*)raw)[i] > 0.5f;
    else                  mv = ((const long long*)raw)[i] != 0;
    madd[i] = mv ? 0.0f : -1e30f;
  }
}

// ---------------------------------------------------------------- f32->bf16
__global__ __launch_bounds__(256) void cvt_bf16(const float* __restrict__ in,
                                                unsigned short* __restrict__ out,
                                                int n8) {
  int i = blockIdx.x * 256 + threadIdx.x;
  int stride = gridDim.x * 256;
  for (; i < n8; i += stride) {
    f32x4 a = *(const f32x4*)(in + (size_t)i * 8);
    f32x4 b = *(const f32x4*)(in + (size_t)i * 8 + 4);
    short8 o;
    o[0] = (short)f2bfbits(a[0]); o[1] = (short)f2bfbits(a[1]);
    o[2] = (short)f2bfbits(a[2]); o[3] = (short)f2bfbits(a[3]);
    o[4] = (short)f2bfbits(b[0]); o[5] = (short)f2bfbits(b[1]);
    o[6] = (short)f2bfbits(b[2]); o[7] = (short)f2bfbits(b[3]);
    *(short8*)(out + (size_t)i * 8) = o;
  }
}

// ---------------------------------------------------------------- GEMM-BT
__global__ __launch_bounds__(256) void gemm_bt16(
    const unsigned short* __restrict__ A, const unsigned short* __restrict__ B,
    const float* __restrict__ bias, float* __restrict__ C,
    unsigned short* __restrict__ vtout, int M, int N, int K, int ldc, int kvmode) {
  __shared__ unsigned short As[128 * 64];
  __shared__ unsigned short Bs[128 * 64];
  const int t = threadIdx.x, l = t & 63, w = t >> 6;
  const int lo = l & 15, hi = l >> 4;
  const int wr = w >> 1, wc = w & 1;
  const int bn = blockIdx.x, bm = blockIdx.y;

  const int sr = l >> 3;
  const int sc = ((l & 7) ^ sr) << 3;
  const unsigned short* Ab = A + (size_t)bm * 128 * K + (size_t)sr * K + sc;
  const unsigned short* Bb = B + (size_t)bn * 128 * K + (size_t)sr * K + sc;

  f32x4 acc[4][4] = {};

  for (int kt = 0; kt < K; kt += 64) {
    __syncthreads();
#pragma unroll
    for (int p = 0; p < 4; ++p) {
      int c = w * 4 + p;
      gload16(Ab + (size_t)c * 8 * K + kt, &As[c * 512]);
      gload16(Bb + (size_t)c * 8 * K + kt, &Bs[c * 512]);
    }
    __syncthreads();
#pragma unroll
    for (int kk = 0; kk < 2; ++kk) {
      short8 af[4], bf[4];
#pragma unroll
      for (int i = 0; i < 4; ++i) {
        int slot = (((kk * 4 + hi) ^ (lo & 7)) << 3);
        af[i] = *(const short8*)&As[(wr * 64 + i * 16 + lo) * 64 + slot];
        bf[i] = *(const short8*)&Bs[(wc * 64 + i * 16 + lo) * 64 + slot];
      }
#pragma unroll
      for (int i = 0; i < 4; ++i)
#pragma unroll
        for (int j = 0; j < 4; ++j)
          acc[i][j] = mfma16(af[i], bf[j], acc[i][j]);
    }
  }

  if (kvmode == 0 || bn < 8) {
#pragma unroll
    for (int j = 0; j < 4; ++j) {
      int col = bn * 128 + wc * 64 + j * 16 + lo;
      float bv = bias[col];
#pragma unroll
      for (int i = 0; i < 4; ++i) {
        int row = bm * 128 + wr * 64 + i * 16 + hi * 4;
#pragma unroll
        for (int r = 0; r < 4; ++r)
          C[(size_t)(row + r) * ldc + col] = acc[i][j][r] + bv;
      }
    }
  } else {
#pragma unroll
    for (int j = 0; j < 4; ++j) {
      int col = bn * 128 + wc * 64 + j * 16 + lo;
      float bv = bias[col];
      int vcol = col - 1024, hh = vcol >> 6, dd = vcol & 63;
#pragma unroll
      for (int i = 0; i < 4; ++i) {
        int row = bm * 128 + wr * 64 + i * 16 + hi * 4;
        int bb = row >= 3072;
        int jj = row - bb * 3072;
        short4v o;
#pragma unroll
        for (int r = 0; r < 4; ++r) o[r] = (short)f2bfbits(acc[i][j][r] + bv);
        *(short4v*)(vtout + ((size_t)((bb * 16 + hh) * 64 + dd)) * 3072 + jj) = o;
      }
    }
  }
}

// ---------------------------------------------------------------- LayerNorm
__global__ __launch_bounds__(256) void ln_head(const float* __restrict__ in,
                                               unsigned short* __restrict__ out,
                                               const float* __restrict__ gw,
                                               const float* __restrict__ gb,
                                               int ngroups, int instride, int rpb,
                                               float outscale) {
  int g = blockIdx.x * 4 + (threadIdx.x >> 6);
  if (g >= ngroups) return;
  int lane = threadIdx.x & 63;
  int row = g >> 4, h = g & 15;
  float v = in[(size_t)row * instride + h * 64 + lane];
  float s = v, sq = v * v;
#pragma unroll
  for (int d = 1; d < 64; d <<= 1) {
    s += __shfl_xor(s, d);
    sq += __shfl_xor(sq, d);
  }
  float mu = s * 0.015625f;
  float var = fmaxf(sq * 0.015625f - mu * mu, 0.0f);
  float rs = rsqrtf(var + 1e-6f);
  float o = ((v - mu) * rs * gw[lane] + gb[lane]) * outscale;
  int b = row / rpb, rr = row - b * rpb;
  out[((size_t)(b * 16 + h) * rpb + rr) * 64 + lane] = f2bfbits(o);
}

// ---------------------------------------------------------------- attention
// Flash attn, swapped QK^T. Grid (32 qb, 32 bh) XCD-swizzled; 4 waves x 16 q.
// K/V tiles (64x64 bf16 each) staged block-wide in LDS, double-buffered,
// global_load_lds w16 with pre-swizzled source (XOR (row&7)<<4 byte swizzle).
// 2-phase pipeline: stage(t+1) -> compute(t) -> syncthreads. P remap via
// wave-private swizzled LDS [16][64]. All LDS reads conflict-free by design.
__global__ __launch_bounds__(256, 4) void attn_fwd(
    const unsigned short* __restrict__ Q, const unsigned short* __restrict__ Kn,
    const unsigned short* __restrict__ Vt, const float* __restrict__ maskAdd,
    unsigned short* __restrict__ ctx) {
  int flat = blockIdx.y * 32 + blockIdx.x;
  int f = (flat & 7) * 128 + (flat >> 3);       // XCD i owns bh in [4i,4i+4)
  const int bh = f >> 5, qb = f & 31;
  const int b = bh >> 4, h = bh & 15;
  const int t = threadIdx.x, l = t & 63, w = t >> 6;
  const int lo = l & 15, hi = l >> 4;
  const int q0 = qb * 64 + w * 16;

  __shared__ unsigned short lds[20480];         // 40 KB exactly
  unsigned short* Ks = lds;                     // [2][64][64]
  unsigned short* Vs = lds + 8192;              // [2][64][64]
  unsigned short* P  = lds + 16384 + w * 1024;  // [16][64] swizzled

  const unsigned short* Qh = Q + ((size_t)bh * 2048 + q0) * 64;
  const unsigned short* Kb = Kn + (size_t)bh * 3072 * 64;
  const unsigned short* Vb = Vt + (size_t)bh * 64 * 3072;
  const float* mb = maskAdd + b * 3072;

  // staging geometry: wave w, instr j in {0,1} covers tile rows j*32+w*8+(l>>3)
  const int srow = w * 8 + (l >> 3);
  const int swz8 = ((l & 7) ^ ((l >> 3) & 7)) << 3;   // swizzled col (shorts)
  const unsigned short* kS = Kb + (size_t)srow * 64 + swz8;
  const unsigned short* vS = Vb + (size_t)srow * 3072 + swz8;
  const int dstoff = w * 512;                   // shorts; +j*2048 per instr

  short8 qf[2];
#pragma unroll
  for (int g = 0; g < 2; g++)
    qf[g] = *(const short8*)(Qh + (size_t)lo * 64 + g * 32 + hi * 8);

  f32x4 O[4] = {};
  float mr = -1e30f, lr = 0.0f;
  const int myswz = (lo & 7) << 3;              // P row swizzle (shorts)

  // prologue: stage tile 0 into buf 0
#pragma unroll
  for (int j = 0; j < 2; ++j) {
    gload16(kS + (size_t)j * 2048, Ks + j * 2048 + dstoff);
    gload16(vS + (size_t)j * 98304, Vs + j * 2048 + dstoff);
  }
  __syncthreads();

  for (int kt = 0; kt < 3072; kt += 64) {
    const int cur = (kt >> 6) & 1;
    const int nxt = cur ^ 1;
    const int ktn = (kt + 64 < 3072) ? kt + 64 : 0;
    // stage next tile (async; drains at the __syncthreads below)
#pragma unroll
    for (int j = 0; j < 2; ++j) {
      gload16(kS + (size_t)ktn * 64 + (size_t)j * 2048, Ks + nxt * 4096 + j * 2048 + dstoff);
      gload16(vS + ktn + (size_t)j * 98304, Vs + nxt * 4096 + j * 2048 + dstoff);
    }

    const unsigned short* Kc = Ks + cur * 4096;
    const unsigned short* Vc = Vs + cur * 4096;

    // QK^T: s[nf] lane(lo,hi) reg r = S[k=kt+16nf+4hi+r][q=q0+lo]
    f32x4 s[4] = {};
#pragma unroll
    for (int nf = 0; nf < 4; nf++) {
      const int row = nf * 16 + lo;
      short8 k0 = *(const short8*)&Kc[row * 64 + (((0 * 32 + hi * 8)) ^ myswz)];
      short8 k1 = *(const short8*)&Kc[row * 64 + (((1 * 32 + hi * 8)) ^ myswz)];
      s[nf] = mfma16(k0, qf[0], s[nf]);
      s[nf] = mfma16(k1, qf[1], s[nf]);
    }
#pragma unroll
    for (int nf = 0; nf < 4; nf++)
      s[nf] += *(const f32x4*)(mb + kt + nf * 16 + hi * 4);

    // online softmax (per q = lo)
    f32x4 x4 = vmax4(vmax4(s[0], s[1]), vmax4(s[2], s[3]));
    float pm = fmaxf(fmaxf(x4[0], x4[1]), fmaxf(x4[2], x4[3]));
    pm = fmaxf(pm, __shfl_xor(pm, 16));
    pm = fmaxf(pm, __shfl_xor(pm, 32));
    if (!__all(pm <= mr + 8.0f)) {              // defer-max (T13)
      float mn = fmaxf(mr, pm);
      float al = __builtin_amdgcn_exp2f(mr - mn);
      mr = mn;
      lr *= al;
      float a0 = __shfl(al, hi * 4 + 0), a1 = __shfl(al, hi * 4 + 1);
      float a2 = __shfl(al, hi * 4 + 2), a3 = __shfl(al, hi * 4 + 3);
#pragma unroll
      for (int df = 0; df < 4; df++) {
        O[df][0] *= a0; O[df][1] *= a1; O[df][2] *= a2; O[df][3] *= a3;
      }
    }
    f32x4 ls = {};
#pragma unroll
    for (int nf = 0; nf < 4; nf++) {
#pragma unroll
      for (int r = 0; r < 4; r++)
        s[nf][r] = __builtin_amdgcn_exp2f(s[nf][r] - mr);
      ls += s[nf];
    }
    float rs = (ls[0] + ls[1]) + (ls[2] + ls[3]);
    rs += __shfl_xor(rs, 16);
    rs += __shfl_xor(rs, 32);
    lr += rs;

    // P[q=lo][k] -> swizzled wave-private LDS
#pragma unroll
    for (int nf = 0; nf < 4; nf++) {
      uint2v u;
      u.x = cvtpk(s[nf][0], s[nf][1]);
      u.y = cvtpk(s[nf][2], s[nf][3]);
      *(uint2v*)&P[lo * 64 + ((nf * 16 + hi * 4) ^ myswz)] = u;
    }
    short8 pa[2];
#pragma unroll
    for (int ks = 0; ks < 2; ks++)
      pa[ks] = *(const short8*)&P[lo * 64 + ((ks * 32 + hi * 8) ^ myswz)];

    // PV: O[q][d] += P[q][k] V[k][d]
#pragma unroll
    for (int df = 0; df < 4; df++) {
      const int row = df * 16 + lo;
#pragma unroll
      for (int ks = 0; ks < 2; ks++) {
        short8 vf = *(const short8*)&Vc[row * 64 + ((ks * 32 + hi * 8) ^ myswz)];
        O[df] = mfma16(pa[ks], vf, O[df]);
      }
    }

    __syncthreads();   // drains vmcnt(0): next tile staged; buf swap safe
  }

  float i0 = 1.0f / __shfl(lr, hi * 4 + 0);
  float i1 = 1.0f / __shfl(lr, hi * 4 + 1);
  float i2 = 1.0f / __shfl(lr, hi * 4 + 2);
  float i3 = 1.0f / __shfl(lr, hi * 4 + 3);
  size_t rbase = (size_t)b * 2048 + q0 + hi * 4;
#pragma unroll
  for (int df = 0; df < 4; df++) {
    int cc = h * 64 + df * 16 + lo;
    ctx[(rbase + 0) * 1024 + cc] = f2bfbits(O[df][0] * i0);
    ctx[(rbase + 1) * 1024 + cc] = f2bfbits(O[df][1] * i1);
    ctx[(rbase + 2) * 1024 + cc] = f2bfbits(O[df][2] * i2);
    ctx[(rbase + 3) * 1024 + cc] = f2bfbits(O[df][3] * i3);
  }
}

// ---------------------------------------------------------------- launch
extern "C" void kernel_launch(void* const* d_in, const int* in_sizes, int n_in,
                              void* d_out, int out_size, void* d_ws, size_t ws_size,
                              hipStream_t stream) {
  const float* x   = (const float*)d_in[0];
  const float* y   = (const float*)d_in[1];
  const unsigned char* pmask = (const unsigned char*)d_in[2];
  const float* Wq  = (const float*)d_in[3];
  const float* bq  = (const float*)d_in[4];
  const float* Wkv = (const float*)d_in[5];
  const float* bkv = (const float*)d_in[6];
  const float* qnw = (const float*)d_in[7];
  const float* qnb = (const float*)d_in[8];
  const float* knw = (const float*)d_in[9];
  const float* knb = (const float*)d_in[10];
  const float* Wo  = (const float*)d_in[11];
  const float* bo  = (const float*)d_in[12];
  float* out = (float*)d_out;

  const size_t MB = 1024ull * 1024ull;
  char* ws = (char*)d_ws;
  float* maskAdd       = (float*)ws;                               // 24 KB
  unsigned short* Wqb  = (unsigned short*)(ws + 32768);            //  2 MiB
  unsigned short* Wkvb = (unsigned short*)(ws + 32768 + 2 * MB);   //  4 MiB
  unsigned short* Wob  = (unsigned short*)(ws + 32768 + 6 * MB);   //  2 MiB
  unsigned short* qln  = (unsigned short*)(ws + 32768 + 8 * MB);   //  8 MiB
  unsigned short* kln  = (unsigned short*)(ws + 32768 + 16 * MB);  // 12 MiB
  unsigned short* vt   = (unsigned short*)(ws + 32768 + 28 * MB);  // 12 MiB
  unsigned short* ctxb = (unsigned short*)(ws + 32768 + 40 * MB);  //  8 MiB
  float* qbuf          = (float*)(ws + 32768 + 48 * MB);           // 16 MiB
  float* kbuf          = (float*)(ws + 32768 + 64 * MB);           // 24 MiB
  unsigned short* xb   = ctxb;  // dead after q-GEMM; ctxb written by attn
  unsigned short* yb   = kln;   // dead after kv-GEMM; kln written by ln_k
  if (ws_size < 32768 + 88 * MB) return;

  prep_mask<<<dim3(1), dim3(256), 0, stream>>>(pmask, maskAdd, 6144);

  cvt_bf16<<<dim3(2048), dim3(256), 0, stream>>>(x,   xb,   4194304 / 8);
  cvt_bf16<<<dim3(2048), dim3(256), 0, stream>>>(y,   yb,   6291456 / 8);
  cvt_bf16<<<dim3(512),  dim3(256), 0, stream>>>(Wq,  Wqb,  1048576 / 8);
  cvt_bf16<<<dim3(1024), dim3(256), 0, stream>>>(Wkv, Wkvb, 2097152 / 8);
  cvt_bf16<<<dim3(512),  dim3(256), 0, stream>>>(Wo,  Wob,  1048576 / 8);

  gemm_bt16<<<dim3(8, 32), dim3(256), 0, stream>>>(xb, Wqb, bq, qbuf, nullptr,
                                                   4096, 1024, 1024, 1024, 0);
  gemm_bt16<<<dim3(16, 48), dim3(256), 0, stream>>>(yb, Wkvb, bkv, kbuf, vt,
                                                    6144, 2048, 1024, 1024, 1);

  ln_head<<<dim3(4096 * 16 / 4), dim3(256), 0, stream>>>(
      qbuf, qln, qnw, qnb, 4096 * 16, 1024, 2048, 0.125f * 1.44269504f);
  ln_head<<<dim3(6144 * 16 / 4), dim3(256), 0, stream>>>(
      kbuf, kln, knw, knb, 6144 * 16, 1024, 3072, 1.0f);

  attn_fwd<<<dim3(32, 32), dim3(256), 0, stream>>>(qln, kln, vt, maskAdd, ctxb);

  gemm_bt16<<<dim3(8, 32), dim3(256), 0, stream>>>(ctxb, Wob, bo, out, nullptr,
                                                   4096, 1024, 1024, 1024, 0);
}